// Round 10
// baseline (407.298 us; speedup 1.0000x reference)
//
#include <hip/hip_runtime.h>
#include <hip/hip_bf16.h>
#include <math.h>

#define H_    16
#define KV_   8
#define D_    128
#define HID_  2048
#define NQKV_ 4096   // H*D + KV*D + KV*D
#define SCALE_ 0.08838834764831845f   // 128^-0.5

typedef __attribute__((ext_vector_type(8))) short bf16x8;
typedef __attribute__((ext_vector_type(4))) float f32x4;
typedef __attribute__((ext_vector_type(4))) short short4v;

__device__ inline unsigned short f2bf(float f) {
  unsigned u = __builtin_bit_cast(unsigned, f);
  u += 0x7FFF + ((u >> 16) & 1);   // RNE
  return (unsigned short)(u >> 16);
}

#define GLDS16(g, l)                                                     \
  __builtin_amdgcn_global_load_lds(                                      \
      (const __attribute__((address_space(1))) void*)(g),                \
      (__attribute__((address_space(3))) void*)(l), 16, 0, 0)

// ---------------- f32 -> bf16 (contiguous, x8 per thread) ----------------
__global__ __launch_bounds__(256) void f32_to_bf16(
    const float* __restrict__ in, unsigned short* __restrict__ out, int n8) {
  int i = blockIdx.x * 256 + threadIdx.x;
  if (i >= n8) return;
  const float4* p = (const float4*)in + (size_t)i * 2;
  float4 a = p[0], b = p[1];
  unsigned short o[8] = {f2bf(a.x), f2bf(a.y), f2bf(a.z), f2bf(a.w),
                         f2bf(b.x), f2bf(b.y), f2bf(b.z), f2bf(b.w)};
  *(bf16x8*)(out + (size_t)i * 8) = *(bf16x8*)o;
}

// ------------- f32 (K x N) -> bf16 transposed (N x K) -------------
__global__ __launch_bounds__(256) void transpose_bf16(
    const float* __restrict__ in, unsigned short* __restrict__ out, int K, int N) {
  __shared__ float t[32][33];
  const int k0 = blockIdx.y * 32, n0 = blockIdx.x * 32;
  const int r = threadIdx.x >> 3, c4 = (threadIdx.x & 7) * 4;
  float4 v = *(const float4*)(in + (size_t)(k0 + r) * N + n0 + c4);
  t[r][c4 + 0] = v.x; t[r][c4 + 1] = v.y; t[r][c4 + 2] = v.z; t[r][c4 + 3] = v.w;
  __syncthreads();
  unsigned short o[4];
#pragma unroll
  for (int j = 0; j < 4; ++j) o[j] = f2bf(t[c4 + j][r]);
  *(short4v*)(out + (size_t)(n0 + r) * K + k0 + c4) = *(short4v*)o;
}

// ------------- merged Wq/Wk/Wv transpose into concatenated (4096, 2048) -------------
__global__ __launch_bounds__(256) void transpose_qkv3(
    const float* __restrict__ Wq, const float* __restrict__ Wk,
    const float* __restrict__ Wv, unsigned short* __restrict__ out) {
  __shared__ float t[32][33];
  const int n0 = blockIdx.x * 32;   // concatenated col
  const int k0 = blockIdx.y * 32;
  const float* src; int N, nloc;
  if (n0 < H_ * D_)                  { src = Wq; N = H_ * D_;  nloc = n0; }
  else if (n0 < H_ * D_ + KV_ * D_)  { src = Wk; N = KV_ * D_; nloc = n0 - H_ * D_; }
  else                               { src = Wv; N = KV_ * D_; nloc = n0 - H_ * D_ - KV_ * D_; }
  const int r = threadIdx.x >> 3, c4 = (threadIdx.x & 7) * 4;
  float4 v = *(const float4*)(src + (size_t)(k0 + r) * N + nloc + c4);
  t[r][c4 + 0] = v.x; t[r][c4 + 1] = v.y; t[r][c4 + 2] = v.z; t[r][c4 + 3] = v.w;
  __syncthreads();
  unsigned short o[4];
#pragma unroll
  for (int j = 0; j < 4; ++j) o[j] = f2bf(t[c4 + j][r]);
  *(short4v*)(out + (size_t)(n0 + r) * HID_ + k0 + c4) = *(short4v*)o;
}

// ======== 256x256x64 bf16 MFMA GEMM, 8 waves, LDS double-buffer, counted vmcnt ========
// (unchanged from round 9 except T1 XCD-aware block swizzle; requires nwg % 8 == 0)
#define QBM 256
#define QBN 256
#define QBK 64

template <int EPI>
__global__ __launch_bounds__(512, 2) void gemm256(
    const unsigned short* __restrict__ A,   // M x K row-major
    const unsigned short* __restrict__ Bt,  // N x K row-major
    float* __restrict__ C0, float* __restrict__ C1,
    unsigned short* __restrict__ C2, int M, int N, int K, int S) {
  __shared__ unsigned short As[2][QBM * QBK];  // 32 KB each
  __shared__ unsigned short Bs[2][QBN * QBK];  // 32 KB each  (total 128 KB)
  const int tid = threadIdx.x;
  const int w = tid >> 6, lane = tid & 63;
  const int wm = w >> 2, wn = w & 3;           // 2 x 4 wave grid
  const int fr = lane & 15, fq = lane >> 4;
  // T1: XCD-aware swizzle (8 XCDs; nwg multiple of 8 -> bijective)
  const int nwg = gridDim.x * gridDim.y;
  const int bid0 = blockIdx.y * gridDim.x + blockIdx.x;
  const int bid = (bid0 & 7) * (nwg >> 3) + (bid0 >> 3);
  const int bx = bid % gridDim.x, by = bid / gridDim.x;
  const int row0 = by * QBM, col0 = bx * QBN;

  const unsigned short* Ab = A + (size_t)row0 * K;
  const unsigned short* Bb = Bt + (size_t)col0 * K;
  const int srow = w * 8 + (lane >> 3);
  const int sc   = lane & 7;
  const int nt   = K / QBK;

  f32x4 acc[8][4] = {};

#define STAGE256(t_, buf_)                                                      \
  {                                                                             \
    const int k0_ = (t_) * QBK;                                                 \
    _Pragma("unroll")                                                           \
    for (int p = 0; p < 4; ++p) {                                               \
      const int r_ = p * 64 + srow;                                             \
      const int gc_ = sc ^ (r_ & 7);                                            \
      GLDS16(Ab + (size_t)r_ * K + k0_ + gc_ * 8,                               \
             &As[buf_][(p * 64 + w * 8) * QBK]);                                \
      GLDS16(Bb + (size_t)r_ * K + k0_ + gc_ * 8,                               \
             &Bs[buf_][(p * 64 + w * 8) * QBK]);                                \
    }                                                                           \
  }

  STAGE256(0, 0);
  STAGE256(1, 1);
  asm volatile("s_waitcnt vmcnt(8)" ::: "memory");   // tile 0 resident
  __builtin_amdgcn_s_barrier();
  __builtin_amdgcn_sched_barrier(0);

  for (int t = 0; t < nt; ++t) {
    const int buf = t & 1;
    __builtin_amdgcn_s_setprio(1);
#pragma unroll
    for (int s = 0; s < 2; ++s) {
      bf16x8 af[8], bf[4];
#pragma unroll
      for (int i = 0; i < 8; ++i) {
        const int r = wm * 128 + i * 16 + fr;
        af[i] = *(const bf16x8*)(&As[buf][r * QBK + (((s << 2) | fq) ^ (r & 7)) * 8]);
      }
#pragma unroll
      for (int j = 0; j < 4; ++j) {
        const int r = wn * 64 + j * 16 + fr;
        bf[j] = *(const bf16x8*)(&Bs[buf][r * QBK + (((s << 2) | fq) ^ (r & 7)) * 8]);
      }
#pragma unroll
      for (int i = 0; i < 8; ++i)
#pragma unroll
        for (int j = 0; j < 4; ++j)
          acc[i][j] = __builtin_amdgcn_mfma_f32_16x16x32_bf16(af[i], bf[j], acc[i][j], 0, 0, 0);
    }
    __builtin_amdgcn_s_setprio(0);
    __builtin_amdgcn_sched_barrier(0);
    __builtin_amdgcn_s_barrier();            // all waves done reading buf
    if (t + 2 < nt) {
      STAGE256(t + 2, buf);
      asm volatile("s_waitcnt vmcnt(8)" ::: "memory");  // tile t+1 resident
    } else {
      asm volatile("s_waitcnt vmcnt(0)" ::: "memory");
    }
    __builtin_amdgcn_s_barrier();            // publish tile t+1
    __builtin_amdgcn_sched_barrier(0);
  }

  if constexpr (EPI == 0) {
#pragma unroll
    for (int i = 0; i < 8; ++i)
#pragma unroll
      for (int j = 0; j < 4; ++j) {
        const int col = col0 + wn * 64 + j * 16 + fr;
#pragma unroll
        for (int r = 0; r < 4; ++r) {
          const int row = row0 + wm * 128 + i * 16 + fq * 4 + r;
          C0[(size_t)row * N + col] = acc[i][j][r];
        }
      }
  } else {
    if (col0 < H_ * D_) {  // Q: f32, ld 2048
#pragma unroll
      for (int i = 0; i < 8; ++i)
#pragma unroll
        for (int j = 0; j < 4; ++j) {
          const int col = col0 + wn * 64 + j * 16 + fr;
#pragma unroll
          for (int r = 0; r < 4; ++r) {
            const int row = row0 + wm * 128 + i * 16 + fq * 4 + r;
            C0[(size_t)row * (H_ * D_) + col] = acc[i][j][r];
          }
        }
    } else if (col0 < H_ * D_ + KV_ * D_) {  // K: f32, ld 1024
#pragma unroll
      for (int i = 0; i < 8; ++i)
#pragma unroll
        for (int j = 0; j < 4; ++j) {
          const int col = col0 - H_ * D_ + wn * 64 + j * 16 + fr;
#pragma unroll
          for (int r = 0; r < 4; ++r) {
            const int row = row0 + wm * 128 + i * 16 + fq * 4 + r;
            C1[(size_t)row * (KV_ * D_) + col] = acc[i][j][r];
          }
        }
    } else {  // V^T bf16: [b*KV+kvh][d][s]
#pragma unroll
      for (int i = 0; i < 8; ++i)
#pragma unroll
        for (int j = 0; j < 4; ++j) {
          const int cc = col0 - (H_ * D_ + KV_ * D_) + wn * 64 + j * 16 + fr;
          const int kvh = cc >> 7, d = cc & 127;
          const int row = row0 + wm * 128 + i * 16 + fq * 4;
          const int b = row / S, s = row - b * S;
          unsigned short o[4] = {f2bf(acc[i][j][0]), f2bf(acc[i][j][1]),
                                 f2bf(acc[i][j][2]), f2bf(acc[i][j][3])};
          *(short4v*)(C2 + ((size_t)(b * KV_ + kvh) * D_ + d) * S + s) = *(short4v*)o;
        }
    }
  }
#undef STAGE256
}

// ------- merged per-head RMSNorm + RoPE for Q and K: f32 in, bf16 out -------
__global__ __launch_bounds__(256) void rmsnorm_rope2(
    const float* __restrict__ qsrc, const float* __restrict__ ksrc,
    unsigned short* __restrict__ qdst, unsigned short* __restrict__ kdst,
    const float* __restrict__ qw, const float* __restrict__ kw,
    const float* __restrict__ cs, const float* __restrict__ sn, int qrows) {
  int row = blockIdx.x * 4 + (threadIdx.x >> 6);
  const int lane = threadIdx.x & 63;
  const float* p; unsigned short* o16; const float* w; int nheads; float oscale;
  if (row < qrows) { p = qsrc; o16 = qdst; w = qw; nheads = H_;  oscale = SCALE_; }
  else { row -= qrows; p = ksrc; o16 = kdst; w = kw; nheads = KV_; oscale = 1.0f; }
  const float* base = p + (size_t)row * D_;
  float x1 = base[lane];
  float x2 = base[lane + 64];
  float ss = x1 * x1 + x2 * x2;
#pragma unroll
  for (int m = 32; m; m >>= 1) ss += __shfl_xor(ss, m);
  float r = rsqrtf(ss * (1.0f / 128.0f) + 1e-6f);
  const size_t sidx = (size_t)(row / nheads) * D_;
  float n1 = x1 * r * w[lane];
  float n2 = x2 * r * w[lane + 64];
  unsigned short* ob = o16 + (size_t)row * D_;
  ob[lane]      = f2bf((n1 * cs[sidx + lane]      - n2 * sn[sidx + lane])      * oscale);
  ob[lane + 64] = f2bf((n2 * cs[sidx + lane + 64] + n1 * sn[sidx + lane + 64]) * oscale);
}

// ======== bf16 MFMA causal flash attention, GQA; QBLK=128 (8 waves), KVBLK=64,
//          K/V LDS double-buffer with counted vmcnt (gemm256 skeleton), defer-max ========
// Pairing: block bid does q-blocks {bid, nqb-1-bid} -> uniform 34 KV-tiles.
// Qb: (B*S,H,D) bf16 (Q pre-scaled); Kb: (B*S,KV,D); Vt: (B*KV,D,S); O bf16.
__global__ __launch_bounds__(512) void flash_bf16(
    const unsigned short* __restrict__ Qb, const unsigned short* __restrict__ Kb,
    const unsigned short* __restrict__ Vt, unsigned short* __restrict__ O, int S) {
  __shared__ unsigned short Kt[2][64 * 128];   // [kv][d] chunk-swizzled, 16 KB each
  __shared__ unsigned short Vs[2][128 * 64];   // [d][kv] chunk-swizzled, 16 KB each
  __shared__ unsigned short Pl[8][16 * 64];    // per-wave P [q][kv] swizzled, 2 KB each
  const int h = blockIdx.y, b = blockIdx.z;
  const int kvh = h >> 1;                      // groups = H/KV = 2
  const int tid = threadIdx.x, w = tid >> 6, lane = tid & 63;
  const int fr = lane & 15, fq = lane >> 4;
  const int nqb = S >> 7;                      // q-blocks of 128
  const unsigned short* vhead = Vt + (size_t)(b * KV_ + kvh) * D_ * S;

  // staging maps (dest = wave-uniform base + lane*16B):
  // K instr p: row p*32 + w*4 + (lane>>4), chunk lane&15; src chunk (c&8)|((c^row)&7)
  // V instr p: row p*64 + w*8 + (lane>>3), chunk lane&7;  src chunk c^(row&7)
#define FSTAGE(t_, buf_)                                                        \
  {                                                                             \
    const int kv0_ = (t_) * 64;                                                 \
    _Pragma("unroll")                                                           \
    for (int p = 0; p < 2; ++p) {                                               \
      const int rk_ = p * 32 + w * 4 + (lane >> 4);                             \
      const int ck_ = lane & 15;                                                \
      const int gk_ = (ck_ & 8) | ((ck_ ^ rk_) & 7);                            \
      GLDS16(Kb + ((size_t)(b * S + kv0_ + rk_) * KV_ + kvh) * D_ + gk_ * 8,    \
             &Kt[buf_][(p * 32 + w * 4) * 128]);                                \
    }                                                                           \
    _Pragma("unroll")                                                           \
    for (int p = 0; p < 2; ++p) {                                               \
      const int rv_ = p * 64 + w * 8 + (lane >> 3);                             \
      const int cv_ = lane & 7;                                                 \
      const int gv_ = cv_ ^ (rv_ & 7);                                          \
      GLDS16(vhead + (size_t)rv_ * S + kv0_ + gv_ * 8,                          \
             &Vs[buf_][(p * 64 + w * 8) * 64]);                                 \
    }                                                                           \
  }

#pragma unroll 1
  for (int half = 0; half < 2; ++half) {
    const int qb = half ? (nqb - 1 - (int)blockIdx.x) : (int)blockIdx.x;
    const int q0 = qb * 128;
    const int nkt = 2 * qb + 2;     // KV-tiles of 64 covering kv <= q0+127

    // Q A-fragments: wave w owns q-rows q0 + w*16 + fr
    bf16x8 qf[4];
    {
      const unsigned short* qp =
          Qb + ((size_t)(b * S + q0 + w * 16 + fr) * H_ + h) * D_;
#pragma unroll
      for (int s = 0; s < 4; ++s) qf[s] = *(const bf16x8*)(qp + s * 32 + fq * 8);
    }

    f32x4 acco[8] = {};   // O[q=fq*4+r][d=16c+fr]
    float mrow[4] = {-1e30f, -1e30f, -1e30f, -1e30f};
    float lrow[4] = {0.f, 0.f, 0.f, 0.f};

    FSTAGE(0, 0);
    FSTAGE(1, 1);
    asm volatile("s_waitcnt vmcnt(4)" ::: "memory");   // tile 0 resident (Q loads older, drained too)
    __builtin_amdgcn_s_barrier();
    __builtin_amdgcn_sched_barrier(0);

#pragma unroll 1
    for (int kt = 0; kt < nkt; ++kt) {
      const int buf = kt & 1;

      // ---- S = Q @ K^T  (C: row=q=fq*4+r, col=kv=16t+fr); Q pre-scaled ----
      f32x4 sa[4];
      __builtin_amdgcn_s_setprio(1);
#pragma unroll
      for (int t = 0; t < 4; ++t) {
        f32x4 a = {};
        const int kv = 16 * t + fr;
#pragma unroll
        for (int s = 0; s < 4; ++s) {
          const int ch = 4 * s + fq;
          const int chs = (ch & 8) | ((ch ^ kv) & 7);
          bf16x8 kf = *(const bf16x8*)(&Kt[buf][kv * 128 + chs * 8]);
          a = __builtin_amdgcn_mfma_f32_16x16x32_bf16(qf[s], kf, a, 0, 0, 0);
        }
        sa[t] = a;
      }
      __builtin_amdgcn_s_setprio(0);

      // causal mask (only the last two tiles can violate)
      if (kt >= 2 * qb) {
#pragma unroll
        for (int t = 0; t < 4; ++t) {
          const int kvg = kt * 64 + 16 * t + fr;
#pragma unroll
          for (int r = 0; r < 4; ++r)
            if (kvg > q0 + w * 16 + fq * 4 + r) sa[t][r] = -1e30f;
        }
      }

      // ---- online softmax with defer-max (THR=8) ----
      float mx[4];
#pragma unroll
      for (int r = 0; r < 4; ++r) {
        float m = fmaxf(fmaxf(sa[0][r], sa[1][r]), fmaxf(sa[2][r], sa[3][r]));
        m = fmaxf(m, __shfl_xor(m, 1));
        m = fmaxf(m, __shfl_xor(m, 2));
        m = fmaxf(m, __shfl_xor(m, 4));
        m = fmaxf(m, __shfl_xor(m, 8));
        mx[r] = m;
      }
      const bool nogrow = (mx[0] <= mrow[0] + 8.f) & (mx[1] <= mrow[1] + 8.f) &
                          (mx[2] <= mrow[2] + 8.f) & (mx[3] <= mrow[3] + 8.f);
      if (__all(nogrow)) {
        // keep old max: P bounded by e^8, no O-rescale
#pragma unroll
        for (int r = 0; r < 4; ++r) {
          float sum = 0.f;
#pragma unroll
          for (int t = 0; t < 4; ++t) {
            const float pv = __expf(sa[t][r] - mrow[r]);
            sa[t][r] = pv;
            sum += pv;
          }
          sum += __shfl_xor(sum, 1);
          sum += __shfl_xor(sum, 2);
          sum += __shfl_xor(sum, 4);
          sum += __shfl_xor(sum, 8);
          lrow[r] += sum;
        }
      } else {
#pragma unroll
        for (int r = 0; r < 4; ++r) {
          const float mn = fmaxf(mrow[r], mx[r]);
          const float al = __expf(mrow[r] - mn);
          mrow[r] = mn;
          float sum = 0.f;
#pragma unroll
          for (int t = 0; t < 4; ++t) {
            const float pv = __expf(sa[t][r] - mn);
            sa[t][r] = pv;
            sum += pv;
          }
          sum += __shfl_xor(sum, 1);
          sum += __shfl_xor(sum, 2);
          sum += __shfl_xor(sum, 4);
          sum += __shfl_xor(sum, 8);
          lrow[r] = lrow[r] * al + sum;
#pragma unroll
          for (int c = 0; c < 8; ++c) acco[c][r] *= al;
        }
      }

      // ---- P -> per-wave LDS (bf16, chunk-swizzled) ----
      unsigned short* pw = &Pl[w][0];
#pragma unroll
      for (int t = 0; t < 4; ++t) {
        const int kv = 16 * t + fr;
        const int ch = kv >> 3;
#pragma unroll
        for (int r = 0; r < 4; ++r) {
          const int q = fq * 4 + r;
          pw[q * 64 + ((ch ^ q) & 7) * 8 + (kv & 7)] = f2bf(sa[t][r]);
        }
      }

      // ---- O += P @ V ----
      bf16x8 pf[2];
#pragma unroll
      for (int s = 0; s < 2; ++s)
        pf[s] = *(const bf16x8*)(pw + fr * 64 + (((4 * s + fq) ^ fr) & 7) * 8);
      __builtin_amdgcn_s_setprio(1);
#pragma unroll
      for (int c = 0; c < 8; ++c) {
        const int d = 16 * c + fr;
#pragma unroll
        for (int s = 0; s < 2; ++s) {
          bf16x8 vf = *(const bf16x8*)(&Vs[buf][d * 64 + (((4 * s + fq) ^ d) & 7) * 8]);
          acco[c] = __builtin_amdgcn_mfma_f32_16x16x32_bf16(pf[s], vf, acco[c], 0, 0, 0);
        }
      }
      __builtin_amdgcn_s_setprio(0);

      // ---- pipeline advance (gemm256 skeleton) ----
      __builtin_amdgcn_sched_barrier(0);
      __builtin_amdgcn_s_barrier();          // all waves done reading buf
      if (kt + 2 < nkt) {
        FSTAGE(kt + 2, buf);                 // overwrite buf with tile kt+2
        asm volatile("s_waitcnt vmcnt(4)" ::: "memory");  // tile kt+1 resident
      } else {
        asm volatile("s_waitcnt vmcnt(0)" ::: "memory");
      }
      __builtin_amdgcn_s_barrier();          // publish tile kt+1
      __builtin_amdgcn_sched_barrier(0);
    }

    // ---- epilogue: O = acc / l, bf16 ----
    float inv[4];
#pragma unroll
    for (int r = 0; r < 4; ++r) inv[r] = 1.0f / lrow[r];
#pragma unroll
    for (int c = 0; c < 8; ++c) {
#pragma unroll
      for (int r = 0; r < 4; ++r) {
        const int q = q0 + w * 16 + fq * 4 + r;
        O[(size_t)(b * S + q) * (H_ * D_) + h * D_ + 16 * c + fr] =
            f2bf(acco[c][r] * inv[r]);
      }
    }
  }
#undef FSTAGE
}

extern "C" void kernel_launch(void* const* d_in, const int* in_sizes, int n_in,
                              void* d_out, int out_size, void* d_ws, size_t ws_size,
                              hipStream_t stream) {
  const float* x  = (const float*)d_in[0];
  const float* sn = (const float*)d_in[1];   // sin
  const float* cs = (const float*)d_in[2];   // cos
  // d_in[3] = attention_mask: causal, applied analytically -> unused
  const float* Wq = (const float*)d_in[4];
  const float* Wk = (const float*)d_in[5];
  const float* Wv = (const float*)d_in[6];
  const float* Wo = (const float*)d_in[7];
  const float* qw = (const float*)d_in[8];
  const float* kw = (const float*)d_in[9];
  float* out = (float*)d_out;

  const int BS = in_sizes[0] / HID_;   // B*S = 4096
  const int S  = in_sizes[3] / BS;     // 2048
  const int B  = BS / S;

  // workspace layout (80 MB total)
  float* kbuf = (float*)d_ws;                                  // BS*KV*D f32  16 MB
  unsigned short* vt   = (unsigned short*)(kbuf + (size_t)BS * KV_ * D_);  // 8 MB
  unsigned short* xb   = vt + (size_t)BS * KV_ * D_;           // BS*HID bf16  16 MB
  unsigned short* wT   = xb + (size_t)BS * HID_;               // 4096*2048 bf16 16 MB
  unsigned short* qb   = wT + (size_t)NQKV_ * HID_;            // BS*H*D bf16  16 MB
  unsigned short* kb16 = qb + (size_t)BS * H_ * D_;            // BS*KV*D bf16  8 MB
  unsigned short* ab16 = xb;                                   // reuse xb after QKV GEMM

  dim3 blk(256);
  const int n8x = BS * HID_ / 8;

  // x -> bf16
  f32_to_bf16<<<dim3(n8x / 256), blk, 0, stream>>>(x, xb, n8x);

  // transpose all three weights into one concatenated (N=4096, K=2048) buffer
  transpose_qkv3<<<dim3(NQKV_ / 32, HID_ / 32), blk, 0, stream>>>(Wq, Wk, Wv, wT);

  // fused QKV GEMM (256^2 pipelined + XCD swizzle): Q f32 -> d_out, K f32 -> kbuf, V^T bf16 -> vt
  gemm256<1><<<dim3(NQKV_ / QBN, BS / QBM), dim3(512), 0, stream>>>(
      xb, wT, out, kbuf, vt, BS, NQKV_, HID_, S);

  // merged per-head RMSNorm + RoPE -> bf16 (SCALE folded into Q)
  rmsnorm_rope2<<<dim3((BS * H_ + BS * KV_) / 4), blk, 0, stream>>>(
      out, kbuf, qb, kb16, qw, kw, cs, sn, BS * H_);

  // causal MFMA flash attention (QBLK=128, KVBLK=64 dbuf, work-balanced pairs) -> bf16
  flash_bf16<<<dim3(S / 256, H_, B), dim3(512), 0, stream>>>(qb, kb16, vt, ab16, S);

  // Out = abuf @ Wo (f32 into d_out); Wo^T reuses wT
  transpose_bf16<<<dim3(HID_ / 32, (H_ * D_) / 32), blk, 0, stream>>>(Wo, wT, H_ * D_, HID_);
  gemm256<0><<<dim3(HID_ / QBN, BS / QBM), dim3(512), 0, stream>>>(
      ab16, wT, out, nullptr, nullptr, BS, HID_, HID_, S);
}